// Round 3
// baseline (131.014 us; speedup 1.0000x reference)
//
#include <hip/hip_runtime.h>
#include <stdint.h>

// CompetitiveNetwork: per-row Sinkhorn-like iteration, MFMA bf16 formulation.
// ROUND 3 = DIFFERENCING EXPERIMENT: kernel identical to R2; launched 4x to
// measure cn_main's true duration (t = (dur - 80.0)/3) past the harness's
// ~41us ws-poison fill that dominates top-5 and hides it.
//
// Single fused kernel: each block (1 wave, 16 rows) redundantly builds the
// shared K-derived bf16 A-fragments from global (K is 16KB -> L2-resident),
// then runs 21 iteration pairs of:
//   D1 = KT x AF ; BF = BT*rcp(D1+1) ; D2 = K x BF ; AF = AT*rcp(D2+1)
// with frag<->frag transpose via v_cvt_pk_bf16_f32 + permlane32/16_swap.
// Tail: final BF and t = (K.W)^T x AF, Y = sum_j BF*t, lane-group reduce.

typedef __attribute__((ext_vector_type(8))) short s8v;   // bf16x8 MFMA operand
typedef __attribute__((ext_vector_type(4))) float f4v;   // fp32x4 MFMA acc
typedef __attribute__((ext_vector_type(4))) unsigned u4v;

#define NPAIR 21   // fori_loop(20) + explicit (BF;AF); final BF fused in tail

__device__ __forceinline__ unsigned cvtpk(float lo, float hi) {
    unsigned r;
    asm("v_cvt_pk_bf16_f32 %0, %1, %2" : "=v"(r) : "v"(lo), "v"(hi));
    return r;
}
__device__ __forceinline__ void swap32(unsigned& a, unsigned& b) {
    asm("v_permlane32_swap_b32 %0, %1" : "+v"(a), "+v"(b));
}
__device__ __forceinline__ void swap16(unsigned& a, unsigned& b) {
    asm("v_permlane16_swap_b32 %0, %1" : "+v"(a), "+v"(b));
}
__device__ __forceinline__ float clipexp(float x) {
    return fminf(__expf(x), 1000.f);   // exp >= 0 always; upper clip only
}
__device__ __forceinline__ float wclip(float x) {
    return fminf(fmaxf(x, -10.f), 10.f);
}

union FragU { unsigned u[4]; s8v s; u4v v; };

// Pack two f32x4 D-tiles (consecutive m-tiles along the next contraction dim)
// into one B-fragment (16 k x 16 n).  D-tile layout: lane(g,r): elem q ->
// (m = t*16 + g*4 + q, col r).  B-frag: lane(g,r): word w -> k = g*8+2w+{lo,hi}.
__device__ __forceinline__ s8v packB(f4v va, f4v vb) {
    unsigned a0 = cvtpk(va[0], va[1]), a1 = cvtpk(va[2], va[3]);
    unsigned b0 = cvtpk(vb[0], vb[1]), b1 = cvtpk(vb[2], vb[3]);
    swap32(a0, b0); swap16(a0, b0);   // a0 -> w0, b0 -> w2
    swap32(a1, b1); swap16(a1, b1);   // a1 -> w1, b1 -> w3
    FragU U; U.u[0] = a0; U.u[1] = a1; U.u[2] = b0; U.u[3] = b1;
    return U.s;
}

__global__ __launch_bounds__(64, 1)
void cn_main(const float* __restrict__ AT,
             const float* __restrict__ Kraw,
             const float* __restrict__ BTraw,
             const float* __restrict__ Wraw,
             const float* __restrict__ braw,
             float* __restrict__ out) {
    const int l  = threadIdx.x;
    const int g  = l >> 4;
    const int r  = l & 15;
    const int rb = blockIdx.x * 16;

    // ---- build A-fragments in registers (redundant per block; K L2-resident)
    // Frag layout (k-convention consistent with packB; any HW k-relabel
    // cancels): frag(mt,kb), lane l: m = mt*16+(l&15),
    //           word w: k = kb*32 + (l>>4)*8 + 2w + {lo,hi}.
    s8v ktA[4][2], kA[4][2], mwtA[4][2];
#pragma unroll
    for (int mt = 0; mt < 4; ++mt) {
        const int mr = mt * 16 + r;
#pragma unroll
        for (int kb = 0; kb < 2; ++kb) {
            FragU ukt, uk, umw;
#pragma unroll
            for (int w = 0; w < 4; ++w) {
                const int k0 = kb * 32 + g * 8 + 2 * w;
                // KT[m=j][k=i] = clipexp(Kraw[i,j]) ; MWT = KT * Wc[i,j]
                const float eT0 = clipexp(Kraw[k0 * 64 + mr]);
                const float eT1 = clipexp(Kraw[(k0 + 1) * 64 + mr]);
                const float w0  = wclip(Wraw[k0 * 64 + mr]);
                const float w1  = wclip(Wraw[(k0 + 1) * 64 + mr]);
                // K[m=i][k=j] = clipexp(Kraw[m, k]) (contiguous pair)
                const float eK0 = clipexp(Kraw[mr * 64 + k0]);
                const float eK1 = clipexp(Kraw[mr * 64 + k0 + 1]);
                ukt.u[w] = cvtpk(eT0, eT1);
                umw.u[w] = cvtpk(eT0 * w0, eT1 * w1);
                uk.u[w]  = cvtpk(eK0, eK1);
            }
            ktA[mt][kb]  = ukt.s;
            kA[mt][kb]   = uk.s;
            mwtA[mt][kb] = umw.s;
        }
    }

    // BT = clipexp(BTraw) at j = jt*16 + g*4 + q
    f4v bt[4];
#pragma unroll
    for (int jt = 0; jt < 4; ++jt) {
        f4v v = *reinterpret_cast<const f4v*>(BTraw + jt * 16 + g * 4);
#pragma unroll
        for (int q = 0; q < 4; ++q) bt[jt][q] = clipexp(v[q]);
    }

    f4v at[4];
#pragma unroll
    for (int it = 0; it < 4; ++it)
        at[it] = *reinterpret_cast<const f4v*>(AT + (rb + r) * 64 + it * 16 + g * 4);

    // AF0 = AT
    s8v afB[2];
    afB[0] = packB(at[0], at[1]);
    afB[1] = packB(at[2], at[3]);

    const f4v zero = {0.f, 0.f, 0.f, 0.f};

#pragma unroll 1
    for (int t = 0; t < NPAIR; ++t) {
        // D1[j,r] = sum_i KT[j,i] * AF[i,r]
        f4v d1[4];
#pragma unroll
        for (int jt = 0; jt < 4; ++jt) {
            f4v acc = zero;
            acc = __builtin_amdgcn_mfma_f32_16x16x32_bf16(ktA[jt][0], afB[0], acc, 0, 0, 0);
            acc = __builtin_amdgcn_mfma_f32_16x16x32_bf16(ktA[jt][1], afB[1], acc, 0, 0, 0);
            d1[jt] = acc;
        }
        // BF = BT * rcp(D1 + 1)
        f4v bf[4];
#pragma unroll
        for (int jt = 0; jt < 4; ++jt)
#pragma unroll
            for (int q = 0; q < 4; ++q)
                bf[jt][q] = bt[jt][q] * __builtin_amdgcn_rcpf(d1[jt][q] + 1.f);
        s8v bfB[2];
        bfB[0] = packB(bf[0], bf[1]);
        bfB[1] = packB(bf[2], bf[3]);
        // D2[i,r] = sum_j K[i,j] * BF[j,r]
        f4v d2[4];
#pragma unroll
        for (int it = 0; it < 4; ++it) {
            f4v acc = zero;
            acc = __builtin_amdgcn_mfma_f32_16x16x32_bf16(kA[it][0], bfB[0], acc, 0, 0, 0);
            acc = __builtin_amdgcn_mfma_f32_16x16x32_bf16(kA[it][1], bfB[1], acc, 0, 0, 0);
            d2[it] = acc;
        }
        // AF = AT * rcp(D2 + 1)
        f4v af[4];
#pragma unroll
        for (int it = 0; it < 4; ++it)
#pragma unroll
            for (int q = 0; q < 4; ++q)
                af[it][q] = at[it][q] * __builtin_amdgcn_rcpf(d2[it][q] + 1.f);
        afB[0] = packB(af[0], af[1]);
        afB[1] = packB(af[2], af[3]);
    }

    // tail: final BF (22nd) and t = MWT x AF, Y = sum_j BF*t
    float y = 0.f;
#pragma unroll
    for (int jt = 0; jt < 4; ++jt) {
        f4v c1 = zero, ct = zero;
        c1 = __builtin_amdgcn_mfma_f32_16x16x32_bf16(ktA[jt][0],  afB[0], c1, 0, 0, 0);
        c1 = __builtin_amdgcn_mfma_f32_16x16x32_bf16(ktA[jt][1],  afB[1], c1, 0, 0, 0);
        ct = __builtin_amdgcn_mfma_f32_16x16x32_bf16(mwtA[jt][0], afB[0], ct, 0, 0, 0);
        ct = __builtin_amdgcn_mfma_f32_16x16x32_bf16(mwtA[jt][1], afB[1], ct, 0, 0, 0);
#pragma unroll
        for (int q = 0; q < 4; ++q)
            y += bt[jt][q] * __builtin_amdgcn_rcpf(c1[q] + 1.f) * ct[q];
    }
    // reduce over lane-groups g (same r)
    y += __shfl_xor(y, 16);
    y += __shfl_xor(y, 32);

    const float bc = fminf(fmaxf(braw[0], -10.f), 10.f);
    if (l < 16) out[rb + l] = y + bc;
}

extern "C" void kernel_launch(void* const* d_in, const int* in_sizes, int n_in,
                              void* d_out, int out_size, void* d_ws, size_t ws_size,
                              hipStream_t stream) {
    (void)in_sizes; (void)n_in; (void)out_size; (void)d_ws; (void)ws_size;
    const float* AT    = (const float*)d_in[0];
    const float* Kraw  = (const float*)d_in[1];
    const float* BTraw = (const float*)d_in[2];
    const float* Wraw  = (const float*)d_in[3];
    const float* braw  = (const float*)d_in[4];

    // 4 identical idempotent launches: t_cn_main = (dur_us - 80.0) / 3.
    for (int rep = 0; rep < 4; ++rep) {
        hipLaunchKernelGGL(cn_main, dim3(16384 / 16), dim3(64), 0, stream,
                           AT, Kraw, BTraw, Wraw, braw, (float*)d_out);
    }
}

// Round 4
// 79.357 us; speedup vs baseline: 1.6509x; 1.6509x over previous
//
#include <hip/hip_runtime.h>
#include <stdint.h>

// CompetitiveNetwork: per-row Sinkhorn-like iteration, MFMA bf16 formulation.
// R4: critical-path surgery. (1) +1 folded into MFMA acc-init; (2) K=64
// contraction split into 2 parallel MFMAs + f4v add (no dependent MFMA chain);
// (3) half-interleaved schedule (d2 MFMAs on bfB0 issue while bf[2..3] rcp/pack
// runs); (4) kA fragments vector-loaded (contiguous rows).
// Wall time = per-wave chain latency (1 wave/SIMD, 1024 waves, 16 rows each;
// occupancy cannot help — every row needs the full 21-pair serial chain).

typedef __attribute__((ext_vector_type(8))) short s8v;   // bf16x8 MFMA operand
typedef __attribute__((ext_vector_type(4))) float f4v;   // fp32x4 MFMA acc
typedef __attribute__((ext_vector_type(4))) unsigned u4v;

#define NPAIR 21   // fori_loop(20) + explicit (BF;AF); final BF fused in tail

__device__ __forceinline__ unsigned cvtpk(float lo, float hi) {
    unsigned r;
    asm("v_cvt_pk_bf16_f32 %0, %1, %2" : "=v"(r) : "v"(lo), "v"(hi));
    return r;
}
__device__ __forceinline__ void swap32(unsigned& a, unsigned& b) {
    asm("v_permlane32_swap_b32 %0, %1" : "+v"(a), "+v"(b));
}
__device__ __forceinline__ void swap16(unsigned& a, unsigned& b) {
    asm("v_permlane16_swap_b32 %0, %1" : "+v"(a), "+v"(b));
}
__device__ __forceinline__ float clipexp(float x) {
    return fminf(__expf(x), 1000.f);   // exp >= 0 always; upper clip only
}
__device__ __forceinline__ float wclip(float x) {
    return fminf(fmaxf(x, -10.f), 10.f);
}

union FragU { unsigned u[4]; s8v s; u4v v; };

// Pack two f32x4 D-tiles (consecutive m-tiles along the next contraction dim)
// into one B-fragment (16 k x 16 n).  D-tile layout: lane(g,r): elem q ->
// (m = t*16 + g*4 + q, col r).  B-frag: lane(g,r): word w -> k = g*8+2w+{lo,hi}.
__device__ __forceinline__ s8v packB(f4v va, f4v vb) {
    unsigned a0 = cvtpk(va[0], va[1]), a1 = cvtpk(va[2], va[3]);
    unsigned b0 = cvtpk(vb[0], vb[1]), b1 = cvtpk(vb[2], vb[3]);
    swap32(a0, b0); swap16(a0, b0);   // a0 -> w0, b0 -> w2
    swap32(a1, b1); swap16(a1, b1);   // a1 -> w1, b1 -> w3
    FragU U; U.u[0] = a0; U.u[1] = a1; U.u[2] = b0; U.u[3] = b1;
    return U.s;
}

__global__ __launch_bounds__(64, 1)
void cn_main(const float* __restrict__ AT,
             const float* __restrict__ Kraw,
             const float* __restrict__ BTraw,
             const float* __restrict__ Wraw,
             const float* __restrict__ braw,
             float* __restrict__ out) {
    const int l  = threadIdx.x;
    const int g  = l >> 4;
    const int r  = l & 15;
    const int rb = blockIdx.x * 16;

    // ---- build A-fragments in registers (redundant per block; K L2-resident)
    // Frag layout (k-convention consistent with packB; any HW k-relabel
    // cancels): frag(mt,kb), lane l: m = mt*16+(l&15),
    //           word w: k = kb*32 + (l>>4)*8 + 2w + {lo,hi}.
    s8v ktA[4][2], kA[4][2], mwtA[4][2];
#pragma unroll
    for (int mt = 0; mt < 4; ++mt) {
        const int mr = mt * 16 + r;
#pragma unroll
        for (int kb = 0; kb < 2; ++kb) {
            // kA: contiguous 8 floats -> two dwordx4 loads
            const f4v kv0 = *reinterpret_cast<const f4v*>(Kraw + mr * 64 + kb * 32 + g * 8);
            const f4v kv1 = *reinterpret_cast<const f4v*>(Kraw + mr * 64 + kb * 32 + g * 8 + 4);
            FragU ukt, uk, umw;
#pragma unroll
            for (int w = 0; w < 4; ++w) {
                const int k0 = kb * 32 + g * 8 + 2 * w;
                // KT[m=j][k=i] = clipexp(Kraw[i,j]) ; MWT = KT * Wc[i,j]
                const float eT0 = clipexp(Kraw[k0 * 64 + mr]);
                const float eT1 = clipexp(Kraw[(k0 + 1) * 64 + mr]);
                const float w0  = wclip(Wraw[k0 * 64 + mr]);
                const float w1  = wclip(Wraw[(k0 + 1) * 64 + mr]);
                const float eK0 = clipexp((w < 2) ? kv0[2 * w] : kv1[2 * w - 4]);
                const float eK1 = clipexp((w < 2) ? kv0[2 * w + 1] : kv1[2 * w - 3]);
                ukt.u[w] = cvtpk(eT0, eT1);
                umw.u[w] = cvtpk(eT0 * w0, eT1 * w1);
                uk.u[w]  = cvtpk(eK0, eK1);
            }
            ktA[mt][kb]  = ukt.s;
            kA[mt][kb]   = uk.s;
            mwtA[mt][kb] = umw.s;
        }
    }

    // BT = clipexp(BTraw) at j = jt*16 + g*4 + q
    f4v bt[4];
#pragma unroll
    for (int jt = 0; jt < 4; ++jt) {
        f4v v = *reinterpret_cast<const f4v*>(BTraw + jt * 16 + g * 4);
#pragma unroll
        for (int q = 0; q < 4; ++q) bt[jt][q] = clipexp(v[q]);
    }

    f4v at[4];
#pragma unroll
    for (int it = 0; it < 4; ++it)
        at[it] = *reinterpret_cast<const f4v*>(AT + (rb + r) * 64 + it * 16 + g * 4);

    // AF0 = AT
    s8v afB[2];
    afB[0] = packB(at[0], at[1]);
    afB[1] = packB(at[2], at[3]);

    const f4v zero = {0.f, 0.f, 0.f, 0.f};
    const f4v ones = {1.f, 1.f, 1.f, 1.f};

#pragma unroll 1
    for (int t = 0; t < NPAIR; ++t) {
        // ---- half 1: D1 = KT·AF + 1  (parallel accs, +1 folded into acc0)
        f4v a0[4], a1[4];
#pragma unroll
        for (int jt = 0; jt < 4; ++jt)
            a0[jt] = __builtin_amdgcn_mfma_f32_16x16x32_bf16(ktA[jt][0], afB[0], ones, 0, 0, 0);
#pragma unroll
        for (int jt = 0; jt < 4; ++jt)
            a1[jt] = __builtin_amdgcn_mfma_f32_16x16x32_bf16(ktA[jt][1], afB[1], zero, 0, 0, 0);

        // BF = BT * rcp(D1); pack low half first, issue d2 MFMAs on it early
        f4v bf0, bf1, bf2, bf3;
        {
            f4v d = a0[0] + a1[0];
#pragma unroll
            for (int q = 0; q < 4; ++q) bf0[q] = bt[0][q] * __builtin_amdgcn_rcpf(d[q]);
        }
        {
            f4v d = a0[1] + a1[1];
#pragma unroll
            for (int q = 0; q < 4; ++q) bf1[q] = bt[1][q] * __builtin_amdgcn_rcpf(d[q]);
        }
        const s8v bfB0 = packB(bf0, bf1);

        f4v c0[4];
#pragma unroll
        for (int it = 0; it < 4; ++it)
            c0[it] = __builtin_amdgcn_mfma_f32_16x16x32_bf16(kA[it][0], bfB0, ones, 0, 0, 0);

        {
            f4v d = a0[2] + a1[2];
#pragma unroll
            for (int q = 0; q < 4; ++q) bf2[q] = bt[2][q] * __builtin_amdgcn_rcpf(d[q]);
        }
        {
            f4v d = a0[3] + a1[3];
#pragma unroll
            for (int q = 0; q < 4; ++q) bf3[q] = bt[3][q] * __builtin_amdgcn_rcpf(d[q]);
        }
        const s8v bfB1 = packB(bf2, bf3);

        f4v c1[4];
#pragma unroll
        for (int it = 0; it < 4; ++it)
            c1[it] = __builtin_amdgcn_mfma_f32_16x16x32_bf16(kA[it][1], bfB1, zero, 0, 0, 0);

        // AF = AT * rcp(D2)
        f4v af[4];
#pragma unroll
        for (int it = 0; it < 4; ++it) {
            f4v d = c0[it] + c1[it];
#pragma unroll
            for (int q = 0; q < 4; ++q)
                af[it][q] = at[it][q] * __builtin_amdgcn_rcpf(d[q]);
        }
        afB[0] = packB(af[0], af[1]);
        afB[1] = packB(af[2], af[3]);
    }

    // tail: final BF (22nd) and t = MWT x AF, Y = sum_j BF*t
    float y = 0.f;
#pragma unroll
    for (int jt = 0; jt < 4; ++jt) {
        f4v c1a, c1b, cta, ctb;
        c1a = __builtin_amdgcn_mfma_f32_16x16x32_bf16(ktA[jt][0],  afB[0], ones, 0, 0, 0);
        c1b = __builtin_amdgcn_mfma_f32_16x16x32_bf16(ktA[jt][1],  afB[1], zero, 0, 0, 0);
        cta = __builtin_amdgcn_mfma_f32_16x16x32_bf16(mwtA[jt][0], afB[0], zero, 0, 0, 0);
        ctb = __builtin_amdgcn_mfma_f32_16x16x32_bf16(mwtA[jt][1], afB[1], zero, 0, 0, 0);
        const f4v den = c1a + c1b;
        const f4v ct  = cta + ctb;
#pragma unroll
        for (int q = 0; q < 4; ++q)
            y += bt[jt][q] * __builtin_amdgcn_rcpf(den[q]) * ct[q];
    }
    // reduce over lane-groups g (same r)
    y += __shfl_xor(y, 16);
    y += __shfl_xor(y, 32);

    const float bc = fminf(fmaxf(braw[0], -10.f), 10.f);
    if (l < 16) out[rb + l] = y + bc;
}

extern "C" void kernel_launch(void* const* d_in, const int* in_sizes, int n_in,
                              void* d_out, int out_size, void* d_ws, size_t ws_size,
                              hipStream_t stream) {
    (void)in_sizes; (void)n_in; (void)out_size; (void)d_ws; (void)ws_size;
    const float* AT    = (const float*)d_in[0];
    const float* Kraw  = (const float*)d_in[1];
    const float* BTraw = (const float*)d_in[2];
    const float* Wraw  = (const float*)d_in[3];
    const float* braw  = (const float*)d_in[4];

    hipLaunchKernelGGL(cn_main, dim3(16384 / 16), dim3(64), 0, stream,
                       AT, Kraw, BTraw, Wraw, braw, (float*)d_out);
}